// Round 5
// baseline (101.305 us; speedup 1.0000x reference)
//
#include <hip/hip_runtime.h>

#define NMS_NUM_CLASSES 16
#define NMS_N 2048
#define NMS_IOU_TH 0.5f
#define NMS_SCORE_TH 0.05f
#define NMS_MAX_DET 100
#define NMS_MAX_PER_CLASS 100
#define NMS_NS (NMS_NUM_CLASSES * NMS_MAX_PER_CLASS)   // 1600
#define NMS_TILE 128

// SESSION PITFALLS (r1-r24):
//  * float4 casts on __shared__ float -> ds_read_b128 misalignment fault.
//  * u64 LDS arrays / LDS pointer casts correlated with container deaths.
//    ONLY declared __shared__ float/uint/uchar arrays, scalar access.
//  * Serial NMS chains cost 45-65 us at M~122 -> Jacobi fixpoint (r15).
//  * Fusion via grid.sync REGRESSED (+5us): launch gaps ~1.4us in graphs.
//  * r20: removing ~6 of ~14 barriers at 16 waves: NO change. Not barriers.
//  * r21/r22: wave-count law T(k1) = 36.5us + 55us/waves. 16 waves best.
//    Single-wave-per-class is DOA: per-wave critical path doesn't shrink
//    with co-residency (r21 91.5us).
//  * r23: branchless 4x-unroll + k2 at 1024thr: 124 -> 93.9. Top-5 now all
//    fillBufferAligned (40us, 256MiB ws poison, 84% HBM peak) -> k1,k2 each
//    < 40us. Old "fixed 73.7us" = fill(40) + k2_old(30) + gaps. Fill is
//    harness-side; our budget is k1 + k2 + gaps.
//  * r24 (this round): k1 rank+scatter fused (one thread per q, full rank,
//    no s_rk/atomics, one fewer barrier); compact without LDS atomics
//    (per-wave counts + broadcast prefix); k2 own-chunk = slot index
//    (sorted-list identity, 15/16 work) + interleaved dual-task ILP.

__device__ __forceinline__ int nms_cmp(float sj, int ij, float sq, int iq) {
    // EXACT r12 comparator semantics, bitwise (no short-circuit branches)
    return ((int)(sj > sq)) | (((int)(sj == sq)) & ((int)(ij < iq)));
}

// ---------------------------------------------------------------------------
// Kernel 1: one block per (image, class), 1024 threads (16 waves).
// ---------------------------------------------------------------------------
__global__ __launch_bounds__(1024) void nms_per_class_kernel(
    const float* __restrict__ pred,   // [B, N, 6] x1,y1,x2,y2,cls,score
    float* __restrict__ ws_scores,    // [B, 1600]
    float* __restrict__ ws_boxes,     // [B, 1600, 4]
    float* __restrict__ out,          // [B*600] rows + [B] nvalid
    int B)
{
    const int b = blockIdx.x / NMS_NUM_CLASSES;
    const int c = blockIdx.x % NMS_NUM_CLASSES;
    const float* p = pred + (size_t)b * NMS_N * 6;
    const int tid = threadIdx.x;
    const int lane = tid & 63;
    const int w = tid >> 6;                  // wave id 0..15

    // zero-init output for this image (k2 is a later dispatch on the stream)
    if (c == 0) {
        float* ob = out + (size_t)b * NMS_MAX_DET * 6;
        for (int t = tid; t < NMS_MAX_DET * 6; t += 1024) ob[t] = 0.0f;
        if (tid == 0) out[(size_t)B * NMS_MAX_DET * 6 + b] = 0.0f;
    }

    __shared__ float s_scu[NMS_N];           // unsorted scores
    __shared__ int   s_ixu[NMS_N];           // unsorted original indices
    __shared__ float s_bxu[NMS_N * 4];       // unsorted boxes
    __shared__ int   s_rk[NMS_N];            // rank accum (M>1024 fallback only)
    __shared__ float s_sc[NMS_N];            // sorted scores
    __shared__ float s_bx[NMS_N * 4];        // sorted boxes
    __shared__ unsigned char s_keep[NMS_N];
    __shared__ unsigned int s_supc[4 * NMS_TILE];  // [window][col], stride-1
    __shared__ int s_wcnt[16];               // per-wave candidate counts

    // ---- compact: atomic-free. Both rows loaded up-front (one vmcnt wait),
    //      per-wave counts -> LDS -> broadcast prefix. 2048 rows, 2/thread. ----
    const float2* p2 = (const float2*)p;     // row i = p2[3i], p2[3i+1], p2[3i+2]
    const int iA = tid, iB = tid + 1024;
    float2 a0 = p2[iA * 3 + 0];              // x1, y1
    float2 a1 = p2[iA * 3 + 1];              // x2, y2
    float2 a2 = p2[iA * 3 + 2];              // cls, score
    float2 b0 = p2[iB * 3 + 0];
    float2 b1 = p2[iB * 3 + 1];
    float2 b2 = p2[iB * 3 + 2];
    const bool okA = ((int)a2.x == c) && (a2.y > NMS_SCORE_TH);
    const bool okB = ((int)b2.x == c) && (b2.y > NMS_SCORE_TH);
    const unsigned long long mA = __ballot(okA);
    const unsigned long long mB = __ballot(okB);
    const int cA = __popcll(mA), cB = __popcll(mB);
    if (lane == 0) s_wcnt[w] = cA + cB;
    __syncthreads();
    int wbase = 0, M = 0;
    for (int ww = 0; ww < 16; ++ww) {        // 16 broadcast reads
        const int v = s_wcnt[ww];
        wbase += (ww < w) ? v : 0;
        M += v;
    }
    const unsigned long long below = (1ull << lane) - 1ull;
    if (okA) {
        const int pos = wbase + __popcll(mA & below);
        s_scu[pos] = a2.y;
        s_ixu[pos] = iA;
        s_bxu[pos * 4 + 0] = a0.x;
        s_bxu[pos * 4 + 1] = a0.y;
        s_bxu[pos * 4 + 2] = a1.x;
        s_bxu[pos * 4 + 3] = a1.y;
    }
    if (okB) {
        const int pos = wbase + cA + __popcll(mB & below);
        s_scu[pos] = b2.y;
        s_ixu[pos] = iB;
        s_bxu[pos * 4 + 0] = b0.x;
        s_bxu[pos * 4 + 1] = b0.y;
        s_bxu[pos * 4 + 2] = b1.x;
        s_bxu[pos * 4 + 3] = b1.y;
    }
    __syncthreads();

    // ---- rank + scatter FUSED (M <= 1024: one thread per q, full rank,
    //      8-wide batched loads, immediate scatter; no atomics, no s_rk) ----
    if (M <= 1024) {
        if (tid < M) {
            const float sq = s_scu[tid];
            const int   iq = s_ixu[tid];
            int r0 = 0, r1 = 0, r2 = 0, r3 = 0;
            int j = 0;
            for (; j + 8 <= M; j += 8) {
                float sa = s_scu[j + 0], sb = s_scu[j + 1];
                float sc2 = s_scu[j + 2], sd = s_scu[j + 3];
                float se = s_scu[j + 4], sf = s_scu[j + 5];
                float sg = s_scu[j + 6], sh = s_scu[j + 7];
                int ia = s_ixu[j + 0], ib2 = s_ixu[j + 1];
                int ic = s_ixu[j + 2], id = s_ixu[j + 3];
                int ie = s_ixu[j + 4], ifx = s_ixu[j + 5];
                int ig = s_ixu[j + 6], ih = s_ixu[j + 7];
                r0 += nms_cmp(sa, ia, sq, iq) + nms_cmp(se, ie, sq, iq);
                r1 += nms_cmp(sb, ib2, sq, iq) + nms_cmp(sf, ifx, sq, iq);
                r2 += nms_cmp(sc2, ic, sq, iq) + nms_cmp(sg, ig, sq, iq);
                r3 += nms_cmp(sd, id, sq, iq) + nms_cmp(sh, ih, sq, iq);
            }
            for (; j < M; ++j)
                r0 += nms_cmp(s_scu[j], s_ixu[j], sq, iq);
            const int rk = (r0 + r1) + (r2 + r3);
            s_sc[rk] = sq;
            s_bx[rk * 4 + 0] = s_bxu[tid * 4 + 0];
            s_bx[rk * 4 + 1] = s_bxu[tid * 4 + 1];
            s_bx[rk * 4 + 2] = s_bxu[tid * 4 + 2];
            s_bx[rk * 4 + 3] = s_bxu[tid * 4 + 3];
            s_keep[rk] = 1;
        }
    } else {
        // general fallback (M > 1024): chunked task-parallel ranks (r23)
        for (int q = tid; q < M; q += 1024) s_rk[q] = 0;
        __syncthreads();
        const int nch = (M + 31) >> 5;
        const int ntask = M * nch;
        for (int task = tid; task < ntask; task += 1024) {
            const int q = task % M;
            const int ch = task / M;
            const float sq = s_scu[q];
            const int   iq = s_ixu[q];
            const int j0 = ch << 5;
            int jend = j0 + 32; if (jend > M) jend = M;
            int rk = 0;
            for (int j = j0; j < jend; ++j)
                rk += nms_cmp(s_scu[j], s_ixu[j], sq, iq);
            if (rk) atomicAdd(&s_rk[q], rk);
        }
        __syncthreads();
        for (int q = tid; q < M; q += 1024) {
            int rk = s_rk[q];
            s_sc[rk] = s_scu[q];
            s_bx[rk * 4 + 0] = s_bxu[q * 4 + 0];
            s_bx[rk * 4 + 1] = s_bxu[q * 4 + 1];
            s_bx[rk * 4 + 2] = s_bxu[q * 4 + 2];
            s_bx[rk * 4 + 3] = s_bxu[q * 4 + 3];
            s_keep[rk] = 1;
        }
    }
    __syncthreads();

    // ---- tiled NMS (r23-proven, incl. multi-tile A0 exercised at M>128) ----
    for (int t0 = 0; t0 < M; t0 += NMS_TILE) {
        const int tm = (M - t0 < NMS_TILE) ? (M - t0) : NMS_TILE;

        // A0: suppression by kept candidates of earlier tiles (final state)
        if (t0 > 0) {
            for (int jj = tid; jj < tm; jj += 1024) {
                const int gj = t0 + jj;
                float jx1 = s_bx[gj * 4 + 0], jy1 = s_bx[gj * 4 + 1];
                float jx2 = s_bx[gj * 4 + 2], jy2 = s_bx[gj * 4 + 3];
                float aj = (jy2 - jy1) * (jx2 - jx1);
                int dead = 0;
                for (int i = 0; i < t0 && !dead; ++i) {
                    if (!s_keep[i]) continue;
                    float ix1 = s_bx[i * 4 + 0], iy1 = s_bx[i * 4 + 1];
                    float ix2 = s_bx[i * 4 + 2], iy2 = s_bx[i * 4 + 3];
                    float ai = (iy2 - iy1) * (ix2 - ix1);
                    float ih = fminf(iy2, jy2) - fmaxf(iy1, jy1);
                    ih = fmaxf(ih, 0.0f);
                    float iw = fminf(ix2, jx2) - fmaxf(ix1, jx1);
                    iw = fmaxf(iw, 0.0f);
                    float inter = ih * iw;
                    float uni = ai + aj - inter;
                    float iou = (inter > 0.0f) ? inter / fmaxf(uni, 1e-08f) : 0.0f;
                    dead = iou > NMS_IOU_TH;
                }
                if (dead) s_keep[gj] = 0;
            }
            __syncthreads();
        }

        // supc: (wi, j) tasks, branchless 4x-unrolled (r23-proven)
        for (int idx = tid; idx < 4 * tm; idx += 1024) {
            const int wi = idx / tm;
            const int jj = idx % tm;
            const int ibase = wi << 5;
            unsigned int m0 = 0, m1 = 0, m2 = 0, m3 = 0;
            int iend = jj - ibase;           // only i < j
            if (iend > 32) iend = 32;
            if (iend > 0) {
                const int gj = t0 + jj;
                float jx1 = s_bx[gj * 4 + 0], jy1 = s_bx[gj * 4 + 1];
                float jx2 = s_bx[gj * 4 + 2], jy2 = s_bx[gj * 4 + 3];
                float aj = (jy2 - jy1) * (jx2 - jx1);
                int bb = 0;
                for (; bb + 4 <= iend; bb += 4) {
#define NMS_SUP1(K, MK)                                                        \
                    {                                                          \
                        const int gi = t0 + ibase + bb + (K);                  \
                        float ix1 = s_bx[gi * 4 + 0], iy1 = s_bx[gi * 4 + 1];  \
                        float ix2 = s_bx[gi * 4 + 2], iy2 = s_bx[gi * 4 + 3];  \
                        float ai = (iy2 - iy1) * (ix2 - ix1);                  \
                        float ih = fminf(iy2, jy2) - fmaxf(iy1, jy1);          \
                        ih = fmaxf(ih, 0.0f);                                  \
                        float iw = fminf(ix2, jx2) - fmaxf(ix1, jx1);          \
                        iw = fmaxf(iw, 0.0f);                                  \
                        float inter = ih * iw;                                 \
                        float uni = ai + aj - inter;                           \
                        float iou = (inter > 0.0f) ? inter / fmaxf(uni, 1e-08f) : 0.0f; \
                        MK |= (iou > NMS_IOU_TH) ? (1u << (bb + (K))) : 0u;    \
                    }
                    NMS_SUP1(0, m0)
                    NMS_SUP1(1, m1)
                    NMS_SUP1(2, m2)
                    NMS_SUP1(3, m3)
                }
                for (; bb < iend; ++bb) {
                    const int gi = t0 + ibase + bb;
                    float ix1 = s_bx[gi * 4 + 0], iy1 = s_bx[gi * 4 + 1];
                    float ix2 = s_bx[gi * 4 + 2], iy2 = s_bx[gi * 4 + 3];
                    float ai = (iy2 - iy1) * (ix2 - ix1);
                    float ih = fminf(iy2, jy2) - fmaxf(iy1, jy1);
                    ih = fmaxf(ih, 0.0f);
                    float iw = fminf(ix2, jx2) - fmaxf(ix1, jx1);
                    iw = fmaxf(iw, 0.0f);
                    float inter = ih * iw;
                    float uni = ai + aj - inter;
                    float iou = (inter > 0.0f) ? inter / fmaxf(uni, 1e-08f) : 0.0f;
                    m0 |= (iou > NMS_IOU_TH) ? (1u << bb) : 0u;
                }
#undef NMS_SUP1
            }
            s_supc[wi * NMS_TILE + jj] = (m0 | m1) | (m2 | m3);
        }
        __syncthreads();                     // supc complete

        // Jacobi fixpoint: wave 0 only, register/ballot-resident (r22-proven)
        if (w == 0) {
            const int j0 = lane, j1 = lane + 64;
            const bool h0 = j0 < tm, h1 = j1 < tm;
            unsigned int m00 = 0, m01 = 0, m02 = 0, m03 = 0;
            unsigned int m10 = 0, m11 = 0, m12 = 0, m13 = 0;
            int ext0 = 0, ext1 = 0;
            if (h0) {
                m00 = s_supc[0 * NMS_TILE + j0];
                m01 = s_supc[1 * NMS_TILE + j0];
                m02 = s_supc[2 * NMS_TILE + j0];
                m03 = s_supc[3 * NMS_TILE + j0];
                ext0 = (int)s_keep[t0 + j0];
            }
            if (h1) {
                m10 = s_supc[0 * NMS_TILE + j1];
                m11 = s_supc[1 * NMS_TILE + j1];
                m12 = s_supc[2 * NMS_TILE + j1];
                m13 = s_supc[3 * NMS_TILE + j1];
                ext1 = (int)s_keep[t0 + j1];
            }
            int alive0 = ext0, alive1 = ext1;
            for (int round = 0; round < NMS_TILE; ++round) {
                unsigned long long A0b = __ballot(alive0 != 0);  // cols 0..63
                unsigned long long A1b = __ballot(alive1 != 0);  // cols 64..127
                const unsigned int kw0 = (unsigned int)(A0b & 0xffffffffu);
                const unsigned int kw1 = (unsigned int)(A0b >> 32);
                const unsigned int kw2 = (unsigned int)(A1b & 0xffffffffu);
                const unsigned int kw3 = (unsigned int)(A1b >> 32);
                int na0 = 0, na1 = 0;
                if (ext0)
                    na0 = (((m00 & kw0) | (m01 & kw1) | (m02 & kw2) | (m03 & kw3)) == 0u);
                if (ext1)
                    na1 = (((m10 & kw0) | (m11 & kw1) | (m12 & kw2) | (m13 & kw3)) == 0u);
                const unsigned long long chg =
                    __ballot(na0 != alive0) | __ballot(na1 != alive1);
                alive0 = na0; alive1 = na1;
                if (chg == 0ull) break;      // uniform within wave
            }
            if (h0) s_keep[t0 + j0] = (unsigned char)alive0;
            if (h1) s_keep[t0 + j1] = (unsigned char)alive1;
        }
        __syncthreads();                     // keep state final for this tile
    }

    // ---- emit top-100 kept in sorted order: wave 0 only (r21-r23-proven) ----
    if (w == 0) {
        const int chunk = (M + 63) >> 6;     // contiguous slots per lane
        int lo = lane * chunk;
        int hi = lo + chunk; if (hi > M) hi = M;
        int cnt2 = 0;
        for (int jj = lo; jj < hi; ++jj) cnt2 += s_keep[jj];
        int inc2 = cnt2;
        for (int off = 1; off < 64; off <<= 1) {
            int n = __shfl_up(inc2, off, 64);
            if (lane >= off) inc2 += n;
        }
        int epos = inc2 - cnt2;              // exclusive prefix
        const int total = __shfl(inc2, 63, 64);

        float* osc = ws_scores + ((size_t)b * NMS_NUM_CLASSES + c) * NMS_MAX_PER_CLASS;
        float* obx = ws_boxes + (((size_t)b * NMS_NUM_CLASSES + c) * NMS_MAX_PER_CLASS) * 4;
        for (int jj = lo; jj < hi; ++jj) {
            if (s_keep[jj]) {
                if (epos < NMS_MAX_PER_CLASS) {
                    osc[epos] = s_sc[jj];
                    obx[epos * 4 + 0] = s_bx[jj * 4 + 0];
                    obx[epos * 4 + 1] = s_bx[jj * 4 + 1];
                    obx[epos * 4 + 2] = s_bx[jj * 4 + 2];
                    obx[epos * 4 + 3] = s_bx[jj * 4 + 3];
                }
                epos++;
            }
        }
        // pad positions [total, 100) with -1
        for (int pp = lane; pp < NMS_MAX_PER_CLASS; pp += 64) {
            if (pp >= total) osc[pp] = -1.0f;
        }
    }
}

// ---------------------------------------------------------------------------
// Kernel 2: one block per (image, class), 1024 threads. Rank semantics
// identical to r12/r23 (same comparator + tie-break), with two exact-work
// reductions: own-class chunk contribution of slot i is EXACTLY i (list is
// sorted desc; j<i ties count via j<flat, j>i ties don't) -> s_rank init = i
// and 15 chunks instead of 16; each thread's two tasks interleaved for ILP.
// ---------------------------------------------------------------------------
__global__ __launch_bounds__(1024) void nms_topk_kernel(
    const float* __restrict__ ws_scores,   // [B, 1600]
    const float* __restrict__ ws_boxes,    // [B, 1600, 4]
    float* __restrict__ out,               // [B*600] rows + [B] nvalid
    int B)
{
    const int b = blockIdx.x / NMS_NUM_CLASSES;
    const int c = blockIdx.x % NMS_NUM_CLASSES;
    const int cbase = c * NMS_MAX_PER_CLASS;
    __shared__ float s_sc[NMS_NS];
    __shared__ int s_rank[NMS_MAX_PER_CLASS];

    const float* isc = ws_scores + (size_t)b * NMS_NS;
    for (int t = threadIdx.x; t < NMS_NS; t += blockDim.x) s_sc[t] = isc[t];
    if (threadIdx.x < NMS_MAX_PER_CLASS) s_rank[threadIdx.x] = threadIdx.x;
    __syncthreads();

    // 1500 tasks = 100 slots x 15 foreign chunks; thread handles tasks
    // tid and tid+1024 (if any) INTERLEAVED (independent load streams).
    {
        const int tA = threadIdx.x;              // always < 1500? (1024 <= 1500 yes)
        const int tB = threadIdx.x + 1024;
        const bool hB = tB < NMS_MAX_PER_CLASS * 15;
        const int slotA = tA % NMS_MAX_PER_CLASS;
        const int chA0 = tA / NMS_MAX_PER_CLASS;
        const int chA = chA0 + (chA0 >= c ? 1 : 0);      // skip own chunk
        const int slotB = hB ? (tB % NMS_MAX_PER_CLASS) : slotA;
        const int chB0 = hB ? (tB / NMS_MAX_PER_CLASS) : chA0;
        const int chB = chB0 + (chB0 >= c ? 1 : 0);
        const int flatA = cbase + slotA;
        const int flatB = cbase + slotB;
        const float sA = s_sc[flatA];
        const float sB = s_sc[flatB];
        const int jA0 = chA * 100;
        const int jB0 = chB * 100;
        int a0 = 0, a1 = 0, a2 = 0, a3 = 0;
        int b0 = 0, b1 = 0, b2 = 0, b3 = 0;
        for (int k = 0; k < 100; k += 4) {
            const int ja = jA0 + k, jb = jB0 + k;
            float va0 = s_sc[ja + 0], va1 = s_sc[ja + 1];
            float va2 = s_sc[ja + 2], va3 = s_sc[ja + 3];
            float vb0 = s_sc[jb + 0], vb1 = s_sc[jb + 1];
            float vb2 = s_sc[jb + 2], vb3 = s_sc[jb + 3];
            a0 += ((int)(va0 > sA)) | (((int)(va0 == sA)) & ((int)(ja + 0 < flatA)));
            a1 += ((int)(va1 > sA)) | (((int)(va1 == sA)) & ((int)(ja + 1 < flatA)));
            a2 += ((int)(va2 > sA)) | (((int)(va2 == sA)) & ((int)(ja + 2 < flatA)));
            a3 += ((int)(va3 > sA)) | (((int)(va3 == sA)) & ((int)(ja + 3 < flatA)));
            b0 += ((int)(vb0 > sB)) | (((int)(vb0 == sB)) & ((int)(jb + 0 < flatB)));
            b1 += ((int)(vb1 > sB)) | (((int)(vb1 == sB)) & ((int)(jb + 1 < flatB)));
            b2 += ((int)(vb2 > sB)) | (((int)(vb2 == sB)) & ((int)(jb + 2 < flatB)));
            b3 += ((int)(vb3 > sB)) | (((int)(vb3 == sB)) & ((int)(jb + 3 < flatB)));
        }
        const int rkA = (a0 + a1) + (a2 + a3);
        const int rkB = (b0 + b1) + (b2 + b3);
        if (rkA) atomicAdd(&s_rank[slotA], rkA);
        if (hB && rkB) atomicAdd(&s_rank[slotB], rkB);
    }
    __syncthreads();

    int is_top = 0;
    const int t = threadIdx.x;
    if (t < NMS_MAX_PER_CLASS) {
        const int slot = cbase + t;
        float s = s_sc[slot];
        if (s > NMS_SCORE_TH) {
            int rk = s_rank[t];
            if (rk < NMS_MAX_DET) {
                const float* bx = ws_boxes + ((size_t)b * NMS_NS + slot) * 4;
                float* row = out + (size_t)b * NMS_MAX_DET * 6 + rk * 6;
                row[0] = bx[0];
                row[1] = bx[1];
                row[2] = bx[2];
                row[3] = bx[3];
                row[4] = (float)c;
                row[5] = s;
                is_top = 1;
            }
        }
    }
    unsigned long long m = __ballot(is_top);
    if ((threadIdx.x & 63) == 0) {
        float cnt = (float)__popcll(m);
        if (cnt > 0.0f)
            atomicAdd(&out[(size_t)B * NMS_MAX_DET * 6 + b], cnt);
    }
}

extern "C" void kernel_launch(void* const* d_in, const int* in_sizes, int n_in,
                              void* d_out, int out_size, void* d_ws, size_t ws_size,
                              hipStream_t stream) {
    const float* pred = (const float*)d_in[0];
    const int B = in_sizes[0] / (NMS_N * 6);
    if (B <= 0) return;
    float* out = (float*)d_out;

    float* ws_scores = (float*)d_ws;
    float* ws_boxes = ws_scores + (size_t)B * NMS_NS;

    nms_per_class_kernel<<<dim3(B * NMS_NUM_CLASSES), dim3(1024), 0, stream>>>(
        pred, ws_scores, ws_boxes, out, B);
    nms_topk_kernel<<<dim3(B * NMS_NUM_CLASSES), dim3(1024), 0, stream>>>(
        ws_scores, ws_boxes, out, B);
}

// Round 6
// 95.654 us; speedup vs baseline: 1.0591x; 1.0591x over previous
//
#include <hip/hip_runtime.h>

#define NMS_NUM_CLASSES 16
#define NMS_N 2048
#define NMS_IOU_TH 0.5f
#define NMS_SCORE_TH 0.05f
#define NMS_MAX_DET 100
#define NMS_MAX_PER_CLASS 100
#define NMS_NS (NMS_NUM_CLASSES * NMS_MAX_PER_CLASS)   // 1600
#define NMS_TILE 128

// SESSION PITFALLS (r1-r25):
//  * float4 casts on __shared__ float -> ds_read_b128 misalignment fault.
//  * u64 LDS arrays / LDS pointer casts correlated with container deaths.
//    ONLY declared __shared__ float/uint/uchar arrays, scalar access.
//  * Serial NMS chains cost 45-65 us at M~122 -> Jacobi fixpoint (r15).
//  * Fusion via grid.sync REGRESSED (+5us): launch gaps ~1.4us in graphs.
//  * r20: removing ~6 of ~14 barriers at 16 waves: NO change. Not barriers.
//  * r21/r22: wave-count law T(k1) = 36.5us + 55us/waves. 16 waves best.
//  * r23: branchless 4x-unroll: 124 -> 93.9 (mostly k2 30 -> ~10).
//  * r24: k1 fused rank (one thread = full M-chain) REGRESSED k1 to 43.6:
//    phase wall time = per-thread dependent-LDS chain length, not total
//    work. Chain law: 122-chain=43.6, 32-chain=~36, inf(1-wave)=91.5.
//  * r25 (this round): revert k1 to r23 structure; halve chains again:
//    rank chunk 32->16 (976 tasks, one/thread), supc windows 32->16 rows
//    (8x16-bit masks, Jacobi recombines pairs into the r23 u32 words,
//    bit-identical layout). k2 stays r24 (passed).

__device__ __forceinline__ int nms_cmp(float sj, int ij, float sq, int iq) {
    // EXACT r12 comparator semantics, bitwise (no short-circuit branches)
    return ((int)(sj > sq)) | (((int)(sj == sq)) & ((int)(ij < iq)));
}

// ---------------------------------------------------------------------------
// Kernel 1: one block per (image, class), 1024 threads (16 waves).
// ---------------------------------------------------------------------------
__global__ __launch_bounds__(1024) void nms_per_class_kernel(
    const float* __restrict__ pred,   // [B, N, 6] x1,y1,x2,y2,cls,score
    float* __restrict__ ws_scores,    // [B, 1600]
    float* __restrict__ ws_boxes,     // [B, 1600, 4]
    float* __restrict__ out,          // [B*600] rows + [B] nvalid
    int B)
{
    const int b = blockIdx.x / NMS_NUM_CLASSES;
    const int c = blockIdx.x % NMS_NUM_CLASSES;
    const float* p = pred + (size_t)b * NMS_N * 6;
    const int tid = threadIdx.x;
    const int lane = tid & 63;
    const int w = tid >> 6;                  // wave id 0..15

    // zero-init output for this image (k2 is a later dispatch on the stream)
    if (c == 0) {
        float* ob = out + (size_t)b * NMS_MAX_DET * 6;
        for (int t = tid; t < NMS_MAX_DET * 6; t += 1024) ob[t] = 0.0f;
        if (tid == 0) out[(size_t)B * NMS_MAX_DET * 6 + b] = 0.0f;
    }

    __shared__ float s_scu[NMS_N];           // unsorted scores
    __shared__ int   s_ixu[NMS_N];           // unsorted original indices
    __shared__ float s_bxu[NMS_N * 4];       // unsorted boxes
    __shared__ int   s_rk[NMS_N];            // rank accumulators
    __shared__ float s_sc[NMS_N];            // sorted scores
    __shared__ float s_bx[NMS_N * 4];        // sorted boxes
    __shared__ unsigned char s_keep[NMS_N];
    __shared__ unsigned int s_supc[8 * NMS_TILE];  // [window16][col], 16-bit masks
    __shared__ int s_m;

    if (tid == 0) s_m = 0;
    __syncthreads();

    // ---- compact: wave-aggregated (r20/r23-proven), s_rk zero fused ----
    const float2* p2 = (const float2*)p;     // row i = p2[3i], p2[3i+1], p2[3i+2]
    for (int i = tid; i < NMS_N; i += 1024) { // uniform trips
        s_rk[i] = 0;
        float2 v0 = p2[i * 3 + 0];           // x1, y1
        float2 v1 = p2[i * 3 + 1];           // x2, y2
        float2 v2 = p2[i * 3 + 2];           // cls, score
        const bool ok = ((int)v2.x == c) && (v2.y > NMS_SCORE_TH);
        unsigned long long mask = __ballot(ok);
        int base = 0;
        if (lane == 0) {
            int cnt = __popcll(mask);
            if (cnt) base = atomicAdd(&s_m, cnt);
        }
        base = __shfl(base, 0, 64);
        if (ok) {
            int pos = base + __popcll(mask & ((1ull << lane) - 1ull));
            s_scu[pos] = v2.y;
            s_ixu[pos] = i;
            s_bxu[pos * 4 + 0] = v0.x;
            s_bxu[pos * 4 + 1] = v0.y;
            s_bxu[pos * 4 + 2] = v1.x;
            s_bxu[pos * 4 + 3] = v1.y;
        }
    }
    __syncthreads();
    const int M = s_m;

    // ---- rank: (q, 16-chunk) tasks, branchless 4x-unrolled inner loop.
    //      M~122 -> 976 tasks, ONE per thread, chain = 16 cmps (4 batches) ----
    {
        const int nch = (M + 15) >> 4;
        const int ntask = M * nch;
        for (int task = tid; task < ntask; task += 1024) {
            const int q = task % M;          // consecutive tids -> distinct q
            const int ch = task / M;
            const float sq = s_scu[q];
            const int   iq = s_ixu[q];
            const int j0 = ch << 4;
            int jend = j0 + 16; if (jend > M) jend = M;
            int r0 = 0, r1 = 0, r2 = 0, r3 = 0;
            int j = j0;
            for (; j + 4 <= jend; j += 4) {
                float sa = s_scu[j + 0], sb = s_scu[j + 1];
                float sc2 = s_scu[j + 2], sd = s_scu[j + 3];
                int ia = s_ixu[j + 0], ib = s_ixu[j + 1];
                int ic = s_ixu[j + 2], id = s_ixu[j + 3];
                r0 += nms_cmp(sa, ia, sq, iq);
                r1 += nms_cmp(sb, ib, sq, iq);
                r2 += nms_cmp(sc2, ic, sq, iq);
                r3 += nms_cmp(sd, id, sq, iq);
            }
            for (; j < jend; ++j)
                r0 += nms_cmp(s_scu[j], s_ixu[j], sq, iq);
            const int rk = (r0 + r1) + (r2 + r3);
            if (rk) atomicAdd(&s_rk[q], rk);
        }
    }
    __syncthreads();
    for (int q = tid; q < M; q += 1024) {
        int rk = s_rk[q];
        s_sc[rk] = s_scu[q];
        s_bx[rk * 4 + 0] = s_bxu[q * 4 + 0];
        s_bx[rk * 4 + 1] = s_bxu[q * 4 + 1];
        s_bx[rk * 4 + 2] = s_bxu[q * 4 + 2];
        s_bx[rk * 4 + 3] = s_bxu[q * 4 + 3];
        s_keep[rk] = 1;
    }
    __syncthreads();

    // ---- tiled NMS ----
    for (int t0 = 0; t0 < M; t0 += NMS_TILE) {
        const int tm = (M - t0 < NMS_TILE) ? (M - t0) : NMS_TILE;

        // A0: suppression by kept candidates of earlier tiles (final state)
        if (t0 > 0) {
            for (int jj = tid; jj < tm; jj += 1024) {
                const int gj = t0 + jj;
                float jx1 = s_bx[gj * 4 + 0], jy1 = s_bx[gj * 4 + 1];
                float jx2 = s_bx[gj * 4 + 2], jy2 = s_bx[gj * 4 + 3];
                float aj = (jy2 - jy1) * (jx2 - jx1);
                int dead = 0;
                for (int i = 0; i < t0 && !dead; ++i) {
                    if (!s_keep[i]) continue;
                    float ix1 = s_bx[i * 4 + 0], iy1 = s_bx[i * 4 + 1];
                    float ix2 = s_bx[i * 4 + 2], iy2 = s_bx[i * 4 + 3];
                    float ai = (iy2 - iy1) * (ix2 - ix1);
                    float ih = fminf(iy2, jy2) - fmaxf(iy1, jy1);
                    ih = fmaxf(ih, 0.0f);
                    float iw = fminf(ix2, jx2) - fmaxf(ix1, jx1);
                    iw = fmaxf(iw, 0.0f);
                    float inter = ih * iw;
                    float uni = ai + aj - inter;
                    float iou = (inter > 0.0f) ? inter / fmaxf(uni, 1e-08f) : 0.0f;
                    dead = iou > NMS_IOU_TH;
                }
                if (dead) s_keep[gj] = 0;
            }
            __syncthreads();
        }

        // supc: (wi, j) tasks over EIGHT 16-row windows; 16-bit masks.
        // M~122 -> 8*122 = 976 tasks, ONE per thread, chain <= 16 IoU.
        for (int idx = tid; idx < 8 * tm; idx += 1024) {
            const int wi = idx / tm;
            const int jj = idx % tm;
            const int ibase = wi << 4;
            unsigned int m0 = 0, m1 = 0, m2 = 0, m3 = 0;
            int iend = jj - ibase;           // only i < j
            if (iend > 16) iend = 16;
            if (iend > 0) {
                const int gj = t0 + jj;
                float jx1 = s_bx[gj * 4 + 0], jy1 = s_bx[gj * 4 + 1];
                float jx2 = s_bx[gj * 4 + 2], jy2 = s_bx[gj * 4 + 3];
                float aj = (jy2 - jy1) * (jx2 - jx1);
                int bb = 0;
                for (; bb + 4 <= iend; bb += 4) {
#define NMS_SUP1(K, MK)                                                        \
                    {                                                          \
                        const int gi = t0 + ibase + bb + (K);                  \
                        float ix1 = s_bx[gi * 4 + 0], iy1 = s_bx[gi * 4 + 1];  \
                        float ix2 = s_bx[gi * 4 + 2], iy2 = s_bx[gi * 4 + 3];  \
                        float ai = (iy2 - iy1) * (ix2 - ix1);                  \
                        float ih = fminf(iy2, jy2) - fmaxf(iy1, jy1);          \
                        ih = fmaxf(ih, 0.0f);                                  \
                        float iw = fminf(ix2, jx2) - fmaxf(ix1, jx1);          \
                        iw = fmaxf(iw, 0.0f);                                  \
                        float inter = ih * iw;                                 \
                        float uni = ai + aj - inter;                           \
                        float iou = (inter > 0.0f) ? inter / fmaxf(uni, 1e-08f) : 0.0f; \
                        MK |= (iou > NMS_IOU_TH) ? (1u << (bb + (K))) : 0u;    \
                    }
                    NMS_SUP1(0, m0)
                    NMS_SUP1(1, m1)
                    NMS_SUP1(2, m2)
                    NMS_SUP1(3, m3)
                }
                for (; bb < iend; ++bb) {
                    const int gi = t0 + ibase + bb;
                    float ix1 = s_bx[gi * 4 + 0], iy1 = s_bx[gi * 4 + 1];
                    float ix2 = s_bx[gi * 4 + 2], iy2 = s_bx[gi * 4 + 3];
                    float ai = (iy2 - iy1) * (ix2 - ix1);
                    float ih = fminf(iy2, jy2) - fmaxf(iy1, jy1);
                    ih = fmaxf(ih, 0.0f);
                    float iw = fminf(ix2, jx2) - fmaxf(ix1, jx1);
                    iw = fmaxf(iw, 0.0f);
                    float inter = ih * iw;
                    float uni = ai + aj - inter;
                    float iou = (inter > 0.0f) ? inter / fmaxf(uni, 1e-08f) : 0.0f;
                    m0 |= (iou > NMS_IOU_TH) ? (1u << bb) : 0u;
                }
#undef NMS_SUP1
            }
            s_supc[wi * NMS_TILE + jj] = (m0 | m1) | (m2 | m3);
        }
        __syncthreads();                     // supc complete

        // Jacobi fixpoint: wave 0 only, register/ballot-resident (r22-proven).
        // Recombine 16-bit window masks into the r23 u32 words:
        // word w rows [32w,32w+32) = window 2w (bits 0-15) | window 2w+1 <<16.
        if (w == 0) {
            const int j0 = lane, j1 = lane + 64;
            const bool h0 = j0 < tm, h1 = j1 < tm;
            unsigned int m00 = 0, m01 = 0, m02 = 0, m03 = 0;
            unsigned int m10 = 0, m11 = 0, m12 = 0, m13 = 0;
            int ext0 = 0, ext1 = 0;
            if (h0) {
                m00 = s_supc[0 * NMS_TILE + j0] | (s_supc[1 * NMS_TILE + j0] << 16);
                m01 = s_supc[2 * NMS_TILE + j0] | (s_supc[3 * NMS_TILE + j0] << 16);
                m02 = s_supc[4 * NMS_TILE + j0] | (s_supc[5 * NMS_TILE + j0] << 16);
                m03 = s_supc[6 * NMS_TILE + j0] | (s_supc[7 * NMS_TILE + j0] << 16);
                ext0 = (int)s_keep[t0 + j0];
            }
            if (h1) {
                m10 = s_supc[0 * NMS_TILE + j1] | (s_supc[1 * NMS_TILE + j1] << 16);
                m11 = s_supc[2 * NMS_TILE + j1] | (s_supc[3 * NMS_TILE + j1] << 16);
                m12 = s_supc[4 * NMS_TILE + j1] | (s_supc[5 * NMS_TILE + j1] << 16);
                m13 = s_supc[6 * NMS_TILE + j1] | (s_supc[7 * NMS_TILE + j1] << 16);
                ext1 = (int)s_keep[t0 + j1];
            }
            int alive0 = ext0, alive1 = ext1;
            for (int round = 0; round < NMS_TILE; ++round) {
                unsigned long long A0b = __ballot(alive0 != 0);  // cols 0..63
                unsigned long long A1b = __ballot(alive1 != 0);  // cols 64..127
                const unsigned int kw0 = (unsigned int)(A0b & 0xffffffffu);
                const unsigned int kw1 = (unsigned int)(A0b >> 32);
                const unsigned int kw2 = (unsigned int)(A1b & 0xffffffffu);
                const unsigned int kw3 = (unsigned int)(A1b >> 32);
                int na0 = 0, na1 = 0;
                if (ext0)
                    na0 = (((m00 & kw0) | (m01 & kw1) | (m02 & kw2) | (m03 & kw3)) == 0u);
                if (ext1)
                    na1 = (((m10 & kw0) | (m11 & kw1) | (m12 & kw2) | (m13 & kw3)) == 0u);
                const unsigned long long chg =
                    __ballot(na0 != alive0) | __ballot(na1 != alive1);
                alive0 = na0; alive1 = na1;
                if (chg == 0ull) break;      // uniform within wave
            }
            if (h0) s_keep[t0 + j0] = (unsigned char)alive0;
            if (h1) s_keep[t0 + j1] = (unsigned char)alive1;
        }
        __syncthreads();                     // keep state final for this tile
    }

    // ---- emit top-100 kept in sorted order: wave 0 only (r21-r23-proven) ----
    if (w == 0) {
        const int chunk = (M + 63) >> 6;     // contiguous slots per lane
        int lo = lane * chunk;
        int hi = lo + chunk; if (hi > M) hi = M;
        int cnt2 = 0;
        for (int jj = lo; jj < hi; ++jj) cnt2 += s_keep[jj];
        int inc2 = cnt2;
        for (int off = 1; off < 64; off <<= 1) {
            int n = __shfl_up(inc2, off, 64);
            if (lane >= off) inc2 += n;
        }
        int epos = inc2 - cnt2;              // exclusive prefix
        const int total = __shfl(inc2, 63, 64);

        float* osc = ws_scores + ((size_t)b * NMS_NUM_CLASSES + c) * NMS_MAX_PER_CLASS;
        float* obx = ws_boxes + (((size_t)b * NMS_NUM_CLASSES + c) * NMS_MAX_PER_CLASS) * 4;
        for (int jj = lo; jj < hi; ++jj) {
            if (s_keep[jj]) {
                if (epos < NMS_MAX_PER_CLASS) {
                    osc[epos] = s_sc[jj];
                    obx[epos * 4 + 0] = s_bx[jj * 4 + 0];
                    obx[epos * 4 + 1] = s_bx[jj * 4 + 1];
                    obx[epos * 4 + 2] = s_bx[jj * 4 + 2];
                    obx[epos * 4 + 3] = s_bx[jj * 4 + 3];
                }
                epos++;
            }
        }
        // pad positions [total, 100) with -1
        for (int pp = lane; pp < NMS_MAX_PER_CLASS; pp += 64) {
            if (pp >= total) osc[pp] = -1.0f;
        }
    }
}

// ---------------------------------------------------------------------------
// Kernel 2: one block per (image, class), 1024 threads. Rank semantics
// identical to r12/r23 (same comparator + tie-break). r24-proven exact-work
// reductions: own-class chunk contribution of slot i is EXACTLY i (sorted
// desc; j<i ties count via j<flat, j>i ties don't) -> s_rank init = i and
// 15 foreign chunks; each thread's two tasks interleaved for ILP.
// ---------------------------------------------------------------------------
__global__ __launch_bounds__(1024) void nms_topk_kernel(
    const float* __restrict__ ws_scores,   // [B, 1600]
    const float* __restrict__ ws_boxes,    // [B, 1600, 4]
    float* __restrict__ out,               // [B*600] rows + [B] nvalid
    int B)
{
    const int b = blockIdx.x / NMS_NUM_CLASSES;
    const int c = blockIdx.x % NMS_NUM_CLASSES;
    const int cbase = c * NMS_MAX_PER_CLASS;
    __shared__ float s_sc[NMS_NS];
    __shared__ int s_rank[NMS_MAX_PER_CLASS];

    const float* isc = ws_scores + (size_t)b * NMS_NS;
    for (int t = threadIdx.x; t < NMS_NS; t += blockDim.x) s_sc[t] = isc[t];
    if (threadIdx.x < NMS_MAX_PER_CLASS) s_rank[threadIdx.x] = threadIdx.x;
    __syncthreads();

    // 1500 tasks = 100 slots x 15 foreign chunks; thread handles tasks
    // tid and tid+1024 (if any) INTERLEAVED (independent load streams).
    {
        const int tA = threadIdx.x;              // 1024 <= 1500, always valid
        const int tB = threadIdx.x + 1024;
        const bool hB = tB < NMS_MAX_PER_CLASS * 15;
        const int slotA = tA % NMS_MAX_PER_CLASS;
        const int chA0 = tA / NMS_MAX_PER_CLASS;
        const int chA = chA0 + (chA0 >= c ? 1 : 0);      // skip own chunk
        const int slotB = hB ? (tB % NMS_MAX_PER_CLASS) : slotA;
        const int chB0 = hB ? (tB / NMS_MAX_PER_CLASS) : chA0;
        const int chB = chB0 + (chB0 >= c ? 1 : 0);
        const int flatA = cbase + slotA;
        const int flatB = cbase + slotB;
        const float sA = s_sc[flatA];
        const float sB = s_sc[flatB];
        const int jA0 = chA * 100;
        const int jB0 = chB * 100;
        int a0 = 0, a1 = 0, a2 = 0, a3 = 0;
        int b0 = 0, b1 = 0, b2 = 0, b3 = 0;
        for (int k = 0; k < 100; k += 4) {
            const int ja = jA0 + k, jb = jB0 + k;
            float va0 = s_sc[ja + 0], va1 = s_sc[ja + 1];
            float va2 = s_sc[ja + 2], va3 = s_sc[ja + 3];
            float vb0 = s_sc[jb + 0], vb1 = s_sc[jb + 1];
            float vb2 = s_sc[jb + 2], vb3 = s_sc[jb + 3];
            a0 += ((int)(va0 > sA)) | (((int)(va0 == sA)) & ((int)(ja + 0 < flatA)));
            a1 += ((int)(va1 > sA)) | (((int)(va1 == sA)) & ((int)(ja + 1 < flatA)));
            a2 += ((int)(va2 > sA)) | (((int)(va2 == sA)) & ((int)(ja + 2 < flatA)));
            a3 += ((int)(va3 > sA)) | (((int)(va3 == sA)) & ((int)(ja + 3 < flatA)));
            b0 += ((int)(vb0 > sB)) | (((int)(vb0 == sB)) & ((int)(jb + 0 < flatB)));
            b1 += ((int)(vb1 > sB)) | (((int)(vb1 == sB)) & ((int)(jb + 1 < flatB)));
            b2 += ((int)(vb2 > sB)) | (((int)(vb2 == sB)) & ((int)(jb + 2 < flatB)));
            b3 += ((int)(vb3 > sB)) | (((int)(vb3 == sB)) & ((int)(jb + 3 < flatB)));
        }
        const int rkA = (a0 + a1) + (a2 + a3);
        const int rkB = (b0 + b1) + (b2 + b3);
        if (rkA) atomicAdd(&s_rank[slotA], rkA);
        if (hB && rkB) atomicAdd(&s_rank[slotB], rkB);
    }
    __syncthreads();

    int is_top = 0;
    const int t = threadIdx.x;
    if (t < NMS_MAX_PER_CLASS) {
        const int slot = cbase + t;
        float s = s_sc[slot];
        if (s > NMS_SCORE_TH) {
            int rk = s_rank[t];
            if (rk < NMS_MAX_DET) {
                const float* bx = ws_boxes + ((size_t)b * NMS_NS + slot) * 4;
                float* row = out + (size_t)b * NMS_MAX_DET * 6 + rk * 6;
                row[0] = bx[0];
                row[1] = bx[1];
                row[2] = bx[2];
                row[3] = bx[3];
                row[4] = (float)c;
                row[5] = s;
                is_top = 1;
            }
        }
    }
    unsigned long long m = __ballot(is_top);
    if ((threadIdx.x & 63) == 0) {
        float cnt = (float)__popcll(m);
        if (cnt > 0.0f)
            atomicAdd(&out[(size_t)B * NMS_MAX_DET * 6 + b], cnt);
    }
}

extern "C" void kernel_launch(void* const* d_in, const int* in_sizes, int n_in,
                              void* d_out, int out_size, void* d_ws, size_t ws_size,
                              hipStream_t stream) {
    const float* pred = (const float*)d_in[0];
    const int B = in_sizes[0] / (NMS_N * 6);
    if (B <= 0) return;
    float* out = (float*)d_out;

    float* ws_scores = (float*)d_ws;
    float* ws_boxes = ws_scores + (size_t)B * NMS_NS;

    nms_per_class_kernel<<<dim3(B * NMS_NUM_CLASSES), dim3(1024), 0, stream>>>(
        pred, ws_scores, ws_boxes, out, B);
    nms_topk_kernel<<<dim3(B * NMS_NUM_CLASSES), dim3(1024), 0, stream>>>(
        ws_scores, ws_boxes, out, B);
}

// Round 7
// 76.375 us; speedup vs baseline: 1.3264x; 1.2524x over previous
//
#include <hip/hip_runtime.h>

#define NMS_NUM_CLASSES 16
#define NMS_N 2048
#define NMS_IOU_TH 0.5f
#define NMS_SCORE_TH 0.05f
#define NMS_MAX_DET 100
#define NMS_MAX_PER_CLASS 100
#define NMS_NS (NMS_NUM_CLASSES * NMS_MAX_PER_CLASS)   // 1600
#define NMS_TILE 192                 // 3 cols/lane; P(M>192) ~ 1e-10

// SESSION PITFALLS (r1-r26):
//  * float4 casts on __shared__ float -> ds_read_b128 misalignment fault.
//  * u64 LDS arrays / LDS pointer casts correlated with container deaths.
//    ONLY declared __shared__ float/uint/uchar arrays, scalar access.
//  * Serial NMS chains cost 45-65 us at M~122 -> Jacobi fixpoint (r15).
//  * Fusion via grid.sync REGRESSED (+5us): launch gaps ~1.4us in graphs.
//  * r20: removing ~6 of ~14 barriers at 16 waves: NO change. Not barriers.
//  * r21/r22: wave-count law T(k1) = 36.5us + 55us/waves. 16 waves best.
//  * r24: one thread = full M-chain REGRESSED (43.6us): wall time = per-
//    thread dependent-LDS chain. r25: chain 32->16 NULL -> saturated <=32.
//  * r26 (this round): duration = MAX over 64 blocks. M ~ Binom, mean 122
//    sd 11 -> max block ~150+ spilled over TILE=128 into tile 2: serial
//    early-exit A0 chain (<=128 LDS-dependent iters) + 2nd supc/Jacobi.
//    Fix: TILE=192 (all realistic blocks single-tile). Jacobi 3 cols/lane,
//    6 keep-words / 3 ballots; supc 6x32-row windows; rank 32-chunks.
//    A0/tile-loop kept as M>192 fallback. If NULL: suspect coupling with
//    the 40us/256MiB harness ws-fill; next = dispatch-split decomposition.

__device__ __forceinline__ int nms_cmp(float sj, int ij, float sq, int iq) {
    // EXACT r12 comparator semantics, bitwise (no short-circuit branches)
    return ((int)(sj > sq)) | (((int)(sj == sq)) & ((int)(ij < iq)));
}

// ---------------------------------------------------------------------------
// Kernel 1: one block per (image, class), 1024 threads (16 waves).
// ---------------------------------------------------------------------------
__global__ __launch_bounds__(1024) void nms_per_class_kernel(
    const float* __restrict__ pred,   // [B, N, 6] x1,y1,x2,y2,cls,score
    float* __restrict__ ws_scores,    // [B, 1600]
    float* __restrict__ ws_boxes,     // [B, 1600, 4]
    float* __restrict__ out,          // [B*600] rows + [B] nvalid
    int B)
{
    const int b = blockIdx.x / NMS_NUM_CLASSES;
    const int c = blockIdx.x % NMS_NUM_CLASSES;
    const float* p = pred + (size_t)b * NMS_N * 6;
    const int tid = threadIdx.x;
    const int lane = tid & 63;
    const int w = tid >> 6;                  // wave id 0..15

    // zero-init output for this image (k2 is a later dispatch on the stream)
    if (c == 0) {
        float* ob = out + (size_t)b * NMS_MAX_DET * 6;
        for (int t = tid; t < NMS_MAX_DET * 6; t += 1024) ob[t] = 0.0f;
        if (tid == 0) out[(size_t)B * NMS_MAX_DET * 6 + b] = 0.0f;
    }

    __shared__ float s_scu[NMS_N];           // unsorted scores
    __shared__ int   s_ixu[NMS_N];           // unsorted original indices
    __shared__ float s_bxu[NMS_N * 4];       // unsorted boxes
    __shared__ int   s_rk[NMS_N];            // rank accumulators
    __shared__ float s_sc[NMS_N];            // sorted scores
    __shared__ float s_bx[NMS_N * 4];        // sorted boxes
    __shared__ unsigned char s_keep[NMS_N];
    __shared__ unsigned int s_supc[6 * NMS_TILE];  // [window32][col] u32 masks
    __shared__ int s_m;

    if (tid == 0) s_m = 0;
    __syncthreads();

    // ---- compact: wave-aggregated (r20/r23-proven), s_rk zero fused ----
    const float2* p2 = (const float2*)p;     // row i = p2[3i], p2[3i+1], p2[3i+2]
    for (int i = tid; i < NMS_N; i += 1024) { // uniform trips
        s_rk[i] = 0;
        float2 v0 = p2[i * 3 + 0];           // x1, y1
        float2 v1 = p2[i * 3 + 1];           // x2, y2
        float2 v2 = p2[i * 3 + 2];           // cls, score
        const bool ok = ((int)v2.x == c) && (v2.y > NMS_SCORE_TH);
        unsigned long long mask = __ballot(ok);
        int base = 0;
        if (lane == 0) {
            int cnt = __popcll(mask);
            if (cnt) base = atomicAdd(&s_m, cnt);
        }
        base = __shfl(base, 0, 64);
        if (ok) {
            int pos = base + __popcll(mask & ((1ull << lane) - 1ull));
            s_scu[pos] = v2.y;
            s_ixu[pos] = i;
            s_bxu[pos * 4 + 0] = v0.x;
            s_bxu[pos * 4 + 1] = v0.y;
            s_bxu[pos * 4 + 2] = v1.x;
            s_bxu[pos * 4 + 3] = v1.y;
        }
    }
    __syncthreads();
    const int M = s_m;

    // ---- rank: (q, 32-chunk) tasks (r23-proven), branchless 4x-unrolled.
    //      M~122 -> 488 tasks, one per thread, chain = 32 cmps ----
    {
        const int nch = (M + 31) >> 5;
        const int ntask = M * nch;
        for (int task = tid; task < ntask; task += 1024) {
            const int q = task % M;          // consecutive tids -> distinct q
            const int ch = task / M;
            const float sq = s_scu[q];
            const int   iq = s_ixu[q];
            const int j0 = ch << 5;
            int jend = j0 + 32; if (jend > M) jend = M;
            int r0 = 0, r1 = 0, r2 = 0, r3 = 0;
            int j = j0;
            for (; j + 4 <= jend; j += 4) {
                float sa = s_scu[j + 0], sb = s_scu[j + 1];
                float sc2 = s_scu[j + 2], sd = s_scu[j + 3];
                int ia = s_ixu[j + 0], ib = s_ixu[j + 1];
                int ic = s_ixu[j + 2], id = s_ixu[j + 3];
                r0 += nms_cmp(sa, ia, sq, iq);
                r1 += nms_cmp(sb, ib, sq, iq);
                r2 += nms_cmp(sc2, ic, sq, iq);
                r3 += nms_cmp(sd, id, sq, iq);
            }
            for (; j < jend; ++j)
                r0 += nms_cmp(s_scu[j], s_ixu[j], sq, iq);
            const int rk = (r0 + r1) + (r2 + r3);
            if (rk) atomicAdd(&s_rk[q], rk);
        }
    }
    __syncthreads();
    for (int q = tid; q < M; q += 1024) {
        int rk = s_rk[q];
        s_sc[rk] = s_scu[q];
        s_bx[rk * 4 + 0] = s_bxu[q * 4 + 0];
        s_bx[rk * 4 + 1] = s_bxu[q * 4 + 1];
        s_bx[rk * 4 + 2] = s_bxu[q * 4 + 2];
        s_bx[rk * 4 + 3] = s_bxu[q * 4 + 3];
        s_keep[rk] = 1;
    }
    __syncthreads();

    // ---- tiled NMS (one tile for all realistic M; loop = M>192 fallback) ----
    for (int t0 = 0; t0 < M; t0 += NMS_TILE) {
        const int tm = (M - t0 < NMS_TILE) ? (M - t0) : NMS_TILE;

        // A0 fallback: suppression by kept candidates of earlier tiles.
        // Never executes for M <= 192 (the benched regime).
        if (t0 > 0) {
            for (int jj = tid; jj < tm; jj += 1024) {
                const int gj = t0 + jj;
                float jx1 = s_bx[gj * 4 + 0], jy1 = s_bx[gj * 4 + 1];
                float jx2 = s_bx[gj * 4 + 2], jy2 = s_bx[gj * 4 + 3];
                float aj = (jy2 - jy1) * (jx2 - jx1);
                int dead = 0;
                for (int i = 0; i < t0 && !dead; ++i) {
                    if (!s_keep[i]) continue;
                    float ix1 = s_bx[i * 4 + 0], iy1 = s_bx[i * 4 + 1];
                    float ix2 = s_bx[i * 4 + 2], iy2 = s_bx[i * 4 + 3];
                    float ai = (iy2 - iy1) * (ix2 - ix1);
                    float ih = fminf(iy2, jy2) - fmaxf(iy1, jy1);
                    ih = fmaxf(ih, 0.0f);
                    float iw = fminf(ix2, jx2) - fmaxf(ix1, jx1);
                    iw = fmaxf(iw, 0.0f);
                    float inter = ih * iw;
                    float uni = ai + aj - inter;
                    float iou = (inter > 0.0f) ? inter / fmaxf(uni, 1e-08f) : 0.0f;
                    dead = iou > NMS_IOU_TH;
                }
                if (dead) s_keep[gj] = 0;
            }
            __syncthreads();
        }

        // supc: (wi, j) tasks over SIX 32-row windows; u32 masks.
        // M~122 -> 6*122 = 732 tasks, one per thread, chain <= 32 IoU.
        for (int idx = tid; idx < 6 * tm; idx += 1024) {
            const int wi = idx / tm;
            const int jj = idx % tm;
            const int ibase = wi << 5;
            unsigned int m0 = 0, m1 = 0, m2 = 0, m3 = 0;
            int iend = jj - ibase;           // only i < j
            if (iend > 32) iend = 32;
            if (iend > 0) {
                const int gj = t0 + jj;
                float jx1 = s_bx[gj * 4 + 0], jy1 = s_bx[gj * 4 + 1];
                float jx2 = s_bx[gj * 4 + 2], jy2 = s_bx[gj * 4 + 3];
                float aj = (jy2 - jy1) * (jx2 - jx1);
                int bb = 0;
                for (; bb + 4 <= iend; bb += 4) {
#define NMS_SUP1(K, MK)                                                        \
                    {                                                          \
                        const int gi = t0 + ibase + bb + (K);                  \
                        float ix1 = s_bx[gi * 4 + 0], iy1 = s_bx[gi * 4 + 1];  \
                        float ix2 = s_bx[gi * 4 + 2], iy2 = s_bx[gi * 4 + 3];  \
                        float ai = (iy2 - iy1) * (ix2 - ix1);                  \
                        float ih = fminf(iy2, jy2) - fmaxf(iy1, jy1);          \
                        ih = fmaxf(ih, 0.0f);                                  \
                        float iw = fminf(ix2, jx2) - fmaxf(ix1, jx1);          \
                        iw = fmaxf(iw, 0.0f);                                  \
                        float inter = ih * iw;                                 \
                        float uni = ai + aj - inter;                           \
                        float iou = (inter > 0.0f) ? inter / fmaxf(uni, 1e-08f) : 0.0f; \
                        MK |= (iou > NMS_IOU_TH) ? (1u << (bb + (K))) : 0u;    \
                    }
                    NMS_SUP1(0, m0)
                    NMS_SUP1(1, m1)
                    NMS_SUP1(2, m2)
                    NMS_SUP1(3, m3)
                }
                for (; bb < iend; ++bb) {
                    const int gi = t0 + ibase + bb;
                    float ix1 = s_bx[gi * 4 + 0], iy1 = s_bx[gi * 4 + 1];
                    float ix2 = s_bx[gi * 4 + 2], iy2 = s_bx[gi * 4 + 3];
                    float ai = (iy2 - iy1) * (ix2 - ix1);
                    float ih = fminf(iy2, jy2) - fmaxf(iy1, jy1);
                    ih = fmaxf(ih, 0.0f);
                    float iw = fminf(ix2, jx2) - fmaxf(ix1, jx1);
                    iw = fmaxf(iw, 0.0f);
                    float inter = ih * iw;
                    float uni = ai + aj - inter;
                    float iou = (inter > 0.0f) ? inter / fmaxf(uni, 1e-08f) : 0.0f;
                    m0 |= (iou > NMS_IOU_TH) ? (1u << bb) : 0u;
                }
#undef NMS_SUP1
            }
            s_supc[wi * NMS_TILE + jj] = (m0 | m1) | (m2 | m3);
        }
        __syncthreads();                     // supc complete

        // Jacobi fixpoint: wave 0 only, register/ballot-resident.
        // 3 columns/lane (lane, +64, +128); 6 keep-words from 3 ballots.
        if (w == 0) {
            const int j0 = lane, j1 = lane + 64, j2 = lane + 128;
            const bool h0 = j0 < tm, h1 = j1 < tm, h2 = j2 < tm;
            unsigned int m00 = 0, m01 = 0, m02 = 0, m03 = 0, m04 = 0, m05 = 0;
            unsigned int m10 = 0, m11 = 0, m12 = 0, m13 = 0, m14 = 0, m15 = 0;
            unsigned int m20 = 0, m21 = 0, m22 = 0, m23 = 0, m24 = 0, m25 = 0;
            int ext0 = 0, ext1 = 0, ext2 = 0;
            if (h0) {
                m00 = s_supc[0 * NMS_TILE + j0];
                m01 = s_supc[1 * NMS_TILE + j0];
                m02 = s_supc[2 * NMS_TILE + j0];
                m03 = s_supc[3 * NMS_TILE + j0];
                m04 = s_supc[4 * NMS_TILE + j0];
                m05 = s_supc[5 * NMS_TILE + j0];
                ext0 = (int)s_keep[t0 + j0];
            }
            if (h1) {
                m10 = s_supc[0 * NMS_TILE + j1];
                m11 = s_supc[1 * NMS_TILE + j1];
                m12 = s_supc[2 * NMS_TILE + j1];
                m13 = s_supc[3 * NMS_TILE + j1];
                m14 = s_supc[4 * NMS_TILE + j1];
                m15 = s_supc[5 * NMS_TILE + j1];
                ext1 = (int)s_keep[t0 + j1];
            }
            if (h2) {
                m20 = s_supc[0 * NMS_TILE + j2];
                m21 = s_supc[1 * NMS_TILE + j2];
                m22 = s_supc[2 * NMS_TILE + j2];
                m23 = s_supc[3 * NMS_TILE + j2];
                m24 = s_supc[4 * NMS_TILE + j2];
                m25 = s_supc[5 * NMS_TILE + j2];
                ext2 = (int)s_keep[t0 + j2];
            }
            int alive0 = ext0, alive1 = ext1, alive2 = ext2;
            for (int round = 0; round < NMS_TILE; ++round) {
                unsigned long long A0b = __ballot(alive0 != 0);  // rows 0..63
                unsigned long long A1b = __ballot(alive1 != 0);  // rows 64..127
                unsigned long long A2b = __ballot(alive2 != 0);  // rows 128..191
                const unsigned int kw0 = (unsigned int)(A0b & 0xffffffffu);
                const unsigned int kw1 = (unsigned int)(A0b >> 32);
                const unsigned int kw2 = (unsigned int)(A1b & 0xffffffffu);
                const unsigned int kw3 = (unsigned int)(A1b >> 32);
                const unsigned int kw4 = (unsigned int)(A2b & 0xffffffffu);
                const unsigned int kw5 = (unsigned int)(A2b >> 32);
                int na0 = 0, na1 = 0, na2 = 0;
                if (ext0)
                    na0 = (((m00 & kw0) | (m01 & kw1) | (m02 & kw2) |
                            (m03 & kw3) | (m04 & kw4) | (m05 & kw5)) == 0u);
                if (ext1)
                    na1 = (((m10 & kw0) | (m11 & kw1) | (m12 & kw2) |
                            (m13 & kw3) | (m14 & kw4) | (m15 & kw5)) == 0u);
                if (ext2)
                    na2 = (((m20 & kw0) | (m21 & kw1) | (m22 & kw2) |
                            (m23 & kw3) | (m24 & kw4) | (m25 & kw5)) == 0u);
                const unsigned long long chg =
                    __ballot(na0 != alive0) | __ballot(na1 != alive1) |
                    __ballot(na2 != alive2);
                alive0 = na0; alive1 = na1; alive2 = na2;
                if (chg == 0ull) break;      // uniform within wave
            }
            if (h0) s_keep[t0 + j0] = (unsigned char)alive0;
            if (h1) s_keep[t0 + j1] = (unsigned char)alive1;
            if (h2) s_keep[t0 + j2] = (unsigned char)alive2;
        }
        __syncthreads();                     // keep state final for this tile
    }

    // ---- emit top-100 kept in sorted order: wave 0 only (r21-r25-proven) ----
    if (w == 0) {
        const int chunk = (M + 63) >> 6;     // contiguous slots per lane
        int lo = lane * chunk;
        int hi = lo + chunk; if (hi > M) hi = M;
        int cnt2 = 0;
        for (int jj = lo; jj < hi; ++jj) cnt2 += s_keep[jj];
        int inc2 = cnt2;
        for (int off = 1; off < 64; off <<= 1) {
            int n = __shfl_up(inc2, off, 64);
            if (lane >= off) inc2 += n;
        }
        int epos = inc2 - cnt2;              // exclusive prefix
        const int total = __shfl(inc2, 63, 64);

        float* osc = ws_scores + ((size_t)b * NMS_NUM_CLASSES + c) * NMS_MAX_PER_CLASS;
        float* obx = ws_boxes + (((size_t)b * NMS_NUM_CLASSES + c) * NMS_MAX_PER_CLASS) * 4;
        for (int jj = lo; jj < hi; ++jj) {
            if (s_keep[jj]) {
                if (epos < NMS_MAX_PER_CLASS) {
                    osc[epos] = s_sc[jj];
                    obx[epos * 4 + 0] = s_bx[jj * 4 + 0];
                    obx[epos * 4 + 1] = s_bx[jj * 4 + 1];
                    obx[epos * 4 + 2] = s_bx[jj * 4 + 2];
                    obx[epos * 4 + 3] = s_bx[jj * 4 + 3];
                }
                epos++;
            }
        }
        // pad positions [total, 100) with -1
        for (int pp = lane; pp < NMS_MAX_PER_CLASS; pp += 64) {
            if (pp >= total) osc[pp] = -1.0f;
        }
    }
}

// ---------------------------------------------------------------------------
// Kernel 2: one block per (image, class), 1024 threads. Rank semantics
// identical to r12/r23 (same comparator + tie-break). r24/r25-proven:
// own-class chunk contribution of slot i is EXACTLY i (sorted desc; j<i
// ties count via j<flat, j>i ties don't) -> s_rank init = i and 15 foreign
// chunks; each thread's two tasks interleaved for ILP.
// ---------------------------------------------------------------------------
__global__ __launch_bounds__(1024) void nms_topk_kernel(
    const float* __restrict__ ws_scores,   // [B, 1600]
    const float* __restrict__ ws_boxes,    // [B, 1600, 4]
    float* __restrict__ out,               // [B*600] rows + [B] nvalid
    int B)
{
    const int b = blockIdx.x / NMS_NUM_CLASSES;
    const int c = blockIdx.x % NMS_NUM_CLASSES;
    const int cbase = c * NMS_MAX_PER_CLASS;
    __shared__ float s_sc[NMS_NS];
    __shared__ int s_rank[NMS_MAX_PER_CLASS];

    const float* isc = ws_scores + (size_t)b * NMS_NS;
    for (int t = threadIdx.x; t < NMS_NS; t += blockDim.x) s_sc[t] = isc[t];
    if (threadIdx.x < NMS_MAX_PER_CLASS) s_rank[threadIdx.x] = threadIdx.x;
    __syncthreads();

    // 1500 tasks = 100 slots x 15 foreign chunks; thread handles tasks
    // tid and tid+1024 (if any) INTERLEAVED (independent load streams).
    {
        const int tA = threadIdx.x;              // 1024 <= 1500, always valid
        const int tB = threadIdx.x + 1024;
        const bool hB = tB < NMS_MAX_PER_CLASS * 15;
        const int slotA = tA % NMS_MAX_PER_CLASS;
        const int chA0 = tA / NMS_MAX_PER_CLASS;
        const int chA = chA0 + (chA0 >= c ? 1 : 0);      // skip own chunk
        const int slotB = hB ? (tB % NMS_MAX_PER_CLASS) : slotA;
        const int chB0 = hB ? (tB / NMS_MAX_PER_CLASS) : chA0;
        const int chB = chB0 + (chB0 >= c ? 1 : 0);
        const int flatA = cbase + slotA;
        const int flatB = cbase + slotB;
        const float sA = s_sc[flatA];
        const float sB = s_sc[flatB];
        const int jA0 = chA * 100;
        const int jB0 = chB * 100;
        int a0 = 0, a1 = 0, a2 = 0, a3 = 0;
        int b0 = 0, b1 = 0, b2 = 0, b3 = 0;
        for (int k = 0; k < 100; k += 4) {
            const int ja = jA0 + k, jb = jB0 + k;
            float va0 = s_sc[ja + 0], va1 = s_sc[ja + 1];
            float va2 = s_sc[ja + 2], va3 = s_sc[ja + 3];
            float vb0 = s_sc[jb + 0], vb1 = s_sc[jb + 1];
            float vb2 = s_sc[jb + 2], vb3 = s_sc[jb + 3];
            a0 += ((int)(va0 > sA)) | (((int)(va0 == sA)) & ((int)(ja + 0 < flatA)));
            a1 += ((int)(va1 > sA)) | (((int)(va1 == sA)) & ((int)(ja + 1 < flatA)));
            a2 += ((int)(va2 > sA)) | (((int)(va2 == sA)) & ((int)(ja + 2 < flatA)));
            a3 += ((int)(va3 > sA)) | (((int)(va3 == sA)) & ((int)(ja + 3 < flatA)));
            b0 += ((int)(vb0 > sB)) | (((int)(vb0 == sB)) & ((int)(jb + 0 < flatB)));
            b1 += ((int)(vb1 > sB)) | (((int)(vb1 == sB)) & ((int)(jb + 1 < flatB)));
            b2 += ((int)(vb2 > sB)) | (((int)(vb2 == sB)) & ((int)(jb + 2 < flatB)));
            b3 += ((int)(vb3 > sB)) | (((int)(vb3 == sB)) & ((int)(jb + 3 < flatB)));
        }
        const int rkA = (a0 + a1) + (a2 + a3);
        const int rkB = (b0 + b1) + (b2 + b3);
        if (rkA) atomicAdd(&s_rank[slotA], rkA);
        if (hB && rkB) atomicAdd(&s_rank[slotB], rkB);
    }
    __syncthreads();

    int is_top = 0;
    const int t = threadIdx.x;
    if (t < NMS_MAX_PER_CLASS) {
        const int slot = cbase + t;
        float s = s_sc[slot];
        if (s > NMS_SCORE_TH) {
            int rk = s_rank[t];
            if (rk < NMS_MAX_DET) {
                const float* bx = ws_boxes + ((size_t)b * NMS_NS + slot) * 4;
                float* row = out + (size_t)b * NMS_MAX_DET * 6 + rk * 6;
                row[0] = bx[0];
                row[1] = bx[1];
                row[2] = bx[2];
                row[3] = bx[3];
                row[4] = (float)c;
                row[5] = s;
                is_top = 1;
            }
        }
    }
    unsigned long long m = __ballot(is_top);
    if ((threadIdx.x & 63) == 0) {
        float cnt = (float)__popcll(m);
        if (cnt > 0.0f)
            atomicAdd(&out[(size_t)B * NMS_MAX_DET * 6 + b], cnt);
    }
}

extern "C" void kernel_launch(void* const* d_in, const int* in_sizes, int n_in,
                              void* d_out, int out_size, void* d_ws, size_t ws_size,
                              hipStream_t stream) {
    const float* pred = (const float*)d_in[0];
    const int B = in_sizes[0] / (NMS_N * 6);
    if (B <= 0) return;
    float* out = (float*)d_out;

    float* ws_scores = (float*)d_ws;
    float* ws_boxes = ws_scores + (size_t)B * NMS_NS;

    nms_per_class_kernel<<<dim3(B * NMS_NUM_CLASSES), dim3(1024), 0, stream>>>(
        pred, ws_scores, ws_boxes, out, B);
    nms_topk_kernel<<<dim3(B * NMS_NUM_CLASSES), dim3(1024), 0, stream>>>(
        ws_scores, ws_boxes, out, B);
}